// Round 4
// baseline (1269.614 us; speedup 1.0000x reference)
//
#include <hip/hip_runtime.h>
#include <hip/hip_bf16.h>

#define N 8192
#define NW 128           // 64-bit mask words per row
#define GR 64            // rows per group
#define GROUPS 128
#define MAXP 1000
typedef unsigned long long u64;

// Static device globals (avoids relying on ws_size). ~8.4 MB total.
__device__ u64    g_key[N];
__device__ float4 g_sboxes[N];
__device__ float  g_sscores[N];
__device__ u64    g_mask[(size_t)N * NW];   // upper-tri blocks only valid
__device__ u64    g_diag[N];                // mask[i][i>>6] (within-group word)
__device__ u64    g_keep[NW];
__device__ int    g_wpre[NW];

// ---- K1: sortable keys. score bits are monotonic for non-negative floats;
// ~bits gives descending score; low 32 = index gives the stable tie-break
// matching jnp.argsort(-scores).
__global__ __launch_bounds__(256) void k_key(const float* __restrict__ scores) {
  int i = blockIdx.x * 256 + threadIdx.x;
  unsigned sb = __float_as_uint(scores[i]);
  g_key[i] = ((u64)(sb ^ 0xFFFFFFFFu) << 32) | (unsigned)i;
}

// ---- K2: O(N^2) rank sort; keys are distinct so ranks form a permutation.
__global__ __launch_bounds__(256) void k_rank(const float4* __restrict__ boxes,
                                              const float* __restrict__ scores) {
  int i = blockIdx.x * 256 + threadIdx.x;
  u64 ki = g_key[i];
  int cnt = 0;
  for (int t = 0; t < N; ++t) cnt += (g_key[t] < ki) ? 1 : 0;
  g_sboxes[cnt] = boxes[i];
  g_sscores[cnt] = scores[i];
}

// ---- K3: 64x64 IoU bit tiles, upper-triangle blocks only (col >= row).
// Bit c of word (i, col) set iff j=col*64+c > i and iou(i,j) > 0.5.
// fp contract OFF so rounding matches numpy exactly. Diagonal word also
// stored compactly in g_diag for the serial kernel's register prefetch.
__global__ __launch_bounds__(64) void k_mask() {
#pragma clang fp contract(off)
  const int col = blockIdx.x, row = blockIdx.y;
  const int t = threadIdx.x;
  if (col < row) return;  // never read
  const int i = row * 64 + t;
  __shared__ float4 cb[64];
  cb[t] = g_sboxes[col * 64 + t];
  __syncthreads();
  float4 bi = g_sboxes[i];
  float areai = (bi.z - bi.x) * (bi.w - bi.y);
  u64 bits = 0;
  for (int c = 0; c < 64; ++c) {
    int j = col * 64 + c;
    if (j <= i) continue;
    float4 bj = cb[c];
    float xx1 = fmaxf(bi.x, bj.x);
    float yy1 = fmaxf(bi.y, bj.y);
    float xx2 = fminf(bi.z, bj.z);
    float yy2 = fminf(bi.w, bj.w);
    float ww = fmaxf(xx2 - xx1, 0.0f);
    float hh = fmaxf(yy2 - yy1, 0.0f);
    float inter = ww * hh;
    float areaj = (bj.z - bj.x) * (bj.w - bj.y);
    float uni = (areai + areaj) - inter;
    float iou = inter / uni;
    if (iou > 0.5f) bits |= (1ull << c);
  }
  g_mask[(size_t)i * NW + col] = bits;
  if (col == row) g_diag[i] = bits;
}

// ---- K4: greedy scan, gather-only. Wave 0 makes serial decisions from a
// register diag word + LDS remv; waves 1-15 gather ONLY kept rows' future
// mask words from global and atomicOr into LDS remv[128]. No tile staging.
__global__ __launch_bounds__(1024) void k_serial3() {
  const int t = threadIdx.x;
  const int wave = t >> 6, lane = t & 63;

  __shared__ u64 remv[NW];
  __shared__ u64 keep_all[NW];
  __shared__ u64 keep_s;

  if (t < NW) { remv[t] = 0; keep_all[t] = 0; }

  u64 dcur = 0, dnext = 0;
  if (wave == 0) dcur = g_diag[lane];   // group 0 diag words
  __syncthreads();

  for (int g = 0; g < GROUPS; ++g) {
    if (wave == 0) {
      // phase 1: serial within-group decisions (uniform scalar loop,
      // ~15 cycles per KEPT box; diag word register-resident)
      u64 pending = ~remv[g];
      u64 mrow = dcur;
      u64 keepm = 0;
      while (pending) {
        int rr = __ffsll((long long)pending) - 1;
        keepm |= (1ull << rr);
        pending &= pending - 1;
        unsigned lo = (unsigned)mrow, hi = (unsigned)(mrow >> 32);
        u64 sup = ((u64)__builtin_amdgcn_readlane(hi, rr) << 32) |
                  (u64)__builtin_amdgcn_readlane(lo, rr);
        pending &= ~sup;
      }
      if (lane == 0) { keep_s = keepm; keep_all[g] = keepm; }
      // prefetch next group's diag words (drains at bar2, overlapped)
      if (g + 1 < GROUPS) dnext = g_diag[(size_t)(g + 1) * 64 + lane];
    }
    __syncthreads();   // bar1: keep_s visible
    if (wave != 0 && g + 1 < GROUPS) {
      // phase 2: kept rows round-robin over waves 1..15; each wave reads
      // its row's words [g+1,128) coalesced (<=2 per lane), ORs into remv.
      u64 keepm = keep_s;
      u64 a0 = 0, a1 = 0;
      int n = 0;
      while (keepm) {
        int rr = __ffsll((long long)keepm) - 1;
        keepm &= keepm - 1;
        if (n % 15 == wave - 1) {
          const u64* rowp = g_mask + (size_t)(g * 64 + rr) * NW;
          int w0 = g + 1 + lane;
          int w1 = w0 + 64;
          if (w0 < NW) a0 |= rowp[w0];
          if (w1 < NW) a1 |= rowp[w1];
        }
        n++;
      }
      int w0 = g + 1 + lane;
      if (a0) atomicOr(&remv[w0], a0);
      if (a1) atomicOr(&remv[w0 + 64], a1);
    }
    if (wave == 0) dcur = dnext;
    __syncthreads();   // bar2: remv updates visible for phase1(g+1)
  }

  // epilogue: keep words + exclusive popcount prefix (wave 0)
  if (wave == 0) {
    u64 k0 = keep_all[2 * lane];
    u64 k1 = keep_all[2 * lane + 1];
    g_keep[2 * lane] = k0;
    g_keep[2 * lane + 1] = k1;
    int pc0 = __popcll(k0);
    int s = pc0 + __popcll(k1);
    int ex = s;
    for (int d = 1; d < 64; d <<= 1) {
      int t2 = __shfl_up(ex, d);
      if (lane >= d) ex += t2;
    }
    ex -= s;
    g_wpre[2 * lane] = ex;
    g_wpre[2 * lane + 1] = ex + pc0;
  }
}

// ---- K5: apply max-proposals cap and write masked rows.
__global__ __launch_bounds__(256) void k_out(float* __restrict__ out) {
  int i = blockIdx.x * 256 + threadIdx.x;
  int w = i >> 6, b = i & 63;
  u64 kw = g_keep[w];
  int before = g_wpre[w] + (b ? __popcll(kw << (64 - b)) : 0);
  bool k = (((kw >> b) & 1ull) != 0ull) && (before < MAXP);
  float m = k ? 1.0f : 0.0f;
  float4 bx = g_sboxes[i];
  float sc = g_sscores[i];
  out[i * 5 + 0] = bx.x * m;
  out[i * 5 + 1] = bx.y * m;
  out[i * 5 + 2] = bx.z * m;
  out[i * 5 + 3] = bx.w * m;
  out[i * 5 + 4] = sc * m;
}

extern "C" void kernel_launch(void* const* d_in, const int* in_sizes, int n_in,
                              void* d_out, int out_size, void* d_ws, size_t ws_size,
                              hipStream_t stream) {
  const float4* boxes = (const float4*)d_in[0];
  const float*  scores = (const float*)d_in[1];
  float* out = (float*)d_out;

  hipLaunchKernelGGL(k_key,     dim3(N / 256), dim3(256),  0, stream, scores);
  hipLaunchKernelGGL(k_rank,    dim3(N / 256), dim3(256),  0, stream, boxes, scores);
  hipLaunchKernelGGL(k_mask,    dim3(NW, NW),  dim3(64),   0, stream);
  hipLaunchKernelGGL(k_serial3, dim3(1),       dim3(1024), 0, stream);
  hipLaunchKernelGGL(k_out,     dim3(N / 256), dim3(256),  0, stream, out);
}

// Round 5
// 694.585 us; speedup vs baseline: 1.8279x; 1.8279x over previous
//
#include <hip/hip_runtime.h>
#include <hip/hip_bf16.h>

#define N 8192
#define NW 128           // 64-bit mask words per row
#define GR 64            // rows per group
#define GROUPS 128
#define MAXP 1000
typedef unsigned long long u64;

// Static device globals (avoids relying on ws_size). ~8.4 MB total.
__device__ u64    g_key[N];
__device__ float4 g_sboxes[N];
__device__ float  g_sscores[N];
__device__ u64    g_mask[(size_t)N * NW];   // upper-tri blocks only valid
__device__ u64    g_diag[N];                // mask[i][i>>6] (within-group word)
__device__ u64    g_keep[NW];
__device__ int    g_wpre[NW];

// ---- K1: sortable keys. score bits are monotonic for non-negative floats;
// ~bits gives descending score; low 32 = index gives the stable tie-break
// matching jnp.argsort(-scores).
__global__ __launch_bounds__(256) void k_key(const float* __restrict__ scores) {
  int i = blockIdx.x * 256 + threadIdx.x;
  unsigned sb = __float_as_uint(scores[i]);
  g_key[i] = ((u64)(sb ^ 0xFFFFFFFFu) << 32) | (unsigned)i;
}

// ---- K2: O(N^2) rank sort; keys are distinct so ranks form a permutation.
__global__ __launch_bounds__(256) void k_rank(const float4* __restrict__ boxes,
                                              const float* __restrict__ scores) {
  int i = blockIdx.x * 256 + threadIdx.x;
  u64 ki = g_key[i];
  int cnt = 0;
  for (int t = 0; t < N; ++t) cnt += (g_key[t] < ki) ? 1 : 0;
  g_sboxes[cnt] = boxes[i];
  g_sscores[cnt] = scores[i];
}

// ---- K3: 64x64 IoU bit tiles, upper-triangle blocks only (col >= row).
// Bit c of word (i, col) set iff j=col*64+c > i and iou(i,j) > 0.5.
// fp contract OFF so rounding matches numpy exactly.
__global__ __launch_bounds__(64) void k_mask() {
#pragma clang fp contract(off)
  const int col = blockIdx.x, row = blockIdx.y;
  const int t = threadIdx.x;
  if (col < row) return;  // never read
  const int i = row * 64 + t;
  __shared__ float4 cb[64];
  cb[t] = g_sboxes[col * 64 + t];
  __syncthreads();
  float4 bi = g_sboxes[i];
  float areai = (bi.z - bi.x) * (bi.w - bi.y);
  u64 bits = 0;
  for (int c = 0; c < 64; ++c) {
    int j = col * 64 + c;
    if (j <= i) continue;
    float4 bj = cb[c];
    float xx1 = fmaxf(bi.x, bj.x);
    float yy1 = fmaxf(bi.y, bj.y);
    float xx2 = fminf(bi.z, bj.z);
    float yy2 = fminf(bi.w, bj.w);
    float ww = fmaxf(xx2 - xx1, 0.0f);
    float hh = fmaxf(yy2 - yy1, 0.0f);
    float inter = ww * hh;
    float areaj = (bj.z - bj.x) * (bj.w - bj.y);
    float uni = (areai + areaj) - inter;
    float iou = inter / uni;
    if (iou > 0.5f) bits |= (1ull << c);
  }
  g_mask[(size_t)i * NW + col] = bits;
  if (col == row) g_diag[i] = bits;
}

__device__ inline u64 shflxor64(u64 v, int m) {
  unsigned lo = (unsigned)v, hi = (unsigned)(v >> 32);
  lo = __shfl_xor(lo, m);
  hi = __shfl_xor(hi, m);
  return ((u64)hi << 32) | lo;
}

// Raw barrier: LDS drain only (no vmcnt(0)), so global prefetch latency spans
// iterations instead of serializing at every barrier. All inter-thread data
// flows through LDS, so skipping the vmcnt drain is safe. "memory" clobbers
// pin compiler ordering around the barrier.
#define WG_BARRIER()                                        \
  do {                                                      \
    asm volatile("s_waitcnt lgkmcnt(0)" ::: "memory");      \
    __builtin_amdgcn_s_barrier();                           \
    asm volatile("" ::: "memory");                          \
  } while (0)

// ---- K4: pipelined greedy scan. 16 waves double-buffer ALIVE rows' mask
// words (>= g+1) through LDS; wave 0 decides keeps from register-resident
// diag words; phase 2 ORs kept rows into LDS remv (8 threads/word).
__global__ __launch_bounds__(1024) void k_serial4() {
  const int t = threadIdx.x;
  const int r = t >> 4;        // row within group (0..63)
  const int c0 = t & 15;       // word-lane (0..15)
  const int wave = t >> 6, lane = t & 63;

  __shared__ u64 buf[2][GR][NW];   // 128 KB double buffer
  __shared__ u64 remv[NW];
  __shared__ u64 keep_all[NW];

  u64 regs[8];
  u64 dcur = 0, dnext = 0;

#define LOADG(G, FILT)                                                   \
  do {                                                                   \
    bool alive_ = true;                                                  \
    if (FILT) alive_ = (((remv[(G)] >> r) & 1ull) == 0ull);              \
    const u64* base_ = g_mask + (size_t)((G) * GR + r) * NW;             \
    _Pragma("unroll")                                                    \
    for (int k = 0; k < 8; ++k) {                                        \
      int w_ = c0 + 16 * k;                                              \
      regs[k] = (alive_ && w_ >= (G) + 1) ? base_[w_] : 0ull;            \
    }                                                                    \
  } while (0)

#define STAGEG(G, P, FILT)                                               \
  do {                                                                   \
    bool alive_ = true;                                                  \
    if (FILT) alive_ = (((remv[(G)] >> r) & 1ull) == 0ull);              \
    if (alive_) {                                                        \
      _Pragma("unroll")                                                  \
      for (int k = 0; k < 8; ++k) buf[P][r][c0 + 16 * k] = regs[k];      \
    }                                                                    \
  } while (0)

  if (t < NW) { remv[t] = 0; keep_all[t] = 0; }
  if (wave == 0) dcur = g_diag[lane];
  LOADG(0, false);
  __syncthreads();           // remv/keep_all init visible
  STAGEG(0, 0, false);
  LOADG(1, true);            // remv all-zero; filter harmless

  for (int g = 0; g < GROUPS; ++g) {
    const int p = g & 1;
    if (g + 1 < GROUPS) STAGEG(g + 1, p ^ 1, true);
    if (g + 2 < GROUPS) LOADG(g + 2, true);
    if (wave == 0) {
      // phase 1: serial within-group decisions from register diag words
      u64 pending = ~remv[g];
      u64 keepm = 0;
      unsigned lo = (unsigned)dcur, hi = (unsigned)(dcur >> 32);
      while (pending) {
        int rr = __ffsll((long long)pending) - 1;
        keepm |= (1ull << rr);
        pending &= pending - 1;
        u64 sup = ((u64)__builtin_amdgcn_readlane(hi, rr) << 32) |
                  (u64)__builtin_amdgcn_readlane(lo, rr);
        pending &= ~sup;
      }
      if (lane == 0) keep_all[g] = keepm;
      if (g + 1 < GROUPS) dnext = g_diag[(size_t)(g + 1) * GR + lane];
    }
    WG_BARRIER();   // bar1: keep_all[g] visible
    {
      // phase 2: OR kept rows into remv for words > g (8 threads per word)
      int w = g + 1 + (t >> 3);
      u64 val = 0;
      int kk = t & 7;
      if (w < NW) {
        u64 stripe = keep_all[g] & (0x0101010101010101ull << kk);
        while (stripe) {
          int rr = __ffsll((long long)stripe) - 1;
          stripe &= stripe - 1;
          val |= buf[p][rr][w];
        }
      }
      val |= shflxor64(val, 1);
      val |= shflxor64(val, 2);
      val |= shflxor64(val, 4);
      if (w < NW && kk == 0) remv[w] |= val;
    }
    if (wave == 0) dcur = dnext;
    WG_BARRIER();   // bar2: remv updates visible for next iteration
  }

  // epilogue: keep words + exclusive popcount prefix (wave 0)
  if (wave == 0) {
    u64 k0 = keep_all[2 * lane];
    u64 k1 = keep_all[2 * lane + 1];
    g_keep[2 * lane] = k0;
    g_keep[2 * lane + 1] = k1;
    int pc0 = __popcll(k0);
    int s = pc0 + __popcll(k1);
    int ex = s;
    for (int d = 1; d < 64; d <<= 1) {
      int t2 = __shfl_up(ex, d);
      if (lane >= d) ex += t2;
    }
    ex -= s;
    g_wpre[2 * lane] = ex;
    g_wpre[2 * lane + 1] = ex + pc0;
  }
}

// ---- K5: apply max-proposals cap and write masked rows.
__global__ __launch_bounds__(256) void k_out(float* __restrict__ out) {
  int i = blockIdx.x * 256 + threadIdx.x;
  int w = i >> 6, b = i & 63;
  u64 kw = g_keep[w];
  int before = g_wpre[w] + (b ? __popcll(kw << (64 - b)) : 0);
  bool k = (((kw >> b) & 1ull) != 0ull) && (before < MAXP);
  float m = k ? 1.0f : 0.0f;
  float4 bx = g_sboxes[i];
  float sc = g_sscores[i];
  out[i * 5 + 0] = bx.x * m;
  out[i * 5 + 1] = bx.y * m;
  out[i * 5 + 2] = bx.z * m;
  out[i * 5 + 3] = bx.w * m;
  out[i * 5 + 4] = sc * m;
}

extern "C" void kernel_launch(void* const* d_in, const int* in_sizes, int n_in,
                              void* d_out, int out_size, void* d_ws, size_t ws_size,
                              hipStream_t stream) {
  const float4* boxes = (const float4*)d_in[0];
  const float*  scores = (const float*)d_in[1];
  float* out = (float*)d_out;

  hipLaunchKernelGGL(k_key,     dim3(N / 256), dim3(256),  0, stream, scores);
  hipLaunchKernelGGL(k_rank,    dim3(N / 256), dim3(256),  0, stream, boxes, scores);
  hipLaunchKernelGGL(k_mask,    dim3(NW, NW),  dim3(64),   0, stream);
  hipLaunchKernelGGL(k_serial4, dim3(1),       dim3(1024), 0, stream);
  hipLaunchKernelGGL(k_out,     dim3(N / 256), dim3(256),  0, stream, out);
}